// Round 8
// baseline (19.576 us; speedup 1.0000x reference)
//
#include <hip/hip_runtime.h>

// YIN pitch, B=8, n=80000, fp32. SR=8000 HOP=80 TAU_MIN=20 TAU_MAX=133 W=133
// FRAME_LEN=266 THRESH=0.2 ; n_frames=997, output 996/batch.
//
// v8 = v7 geometry (64-thr blocks, 4 frames/wave, 16-lane quarter per frame,
// 8 tau/lane) + v5 correlation math:
//   d(tau) = EA + EB(tau) - 2 r(tau)
//   r_k    = sum_j f[j]*stream[j+k]        (32 fma / 4-j chunk, no subs)
//   EA     = sum_{j<=132} f[j]^2           (4 fma/chunk on bcast operand, uniform)
//   EB_tau = EA + prefix_{t<=tau} D_t,  D_t = x[t+132]^2 - x[t-1]^2
//            (per-lane D_k from register stream values + scan16)
// Tail taus 129..133 direct-form j-split; cmndf prefix + min-pick epilogue
// verbatim from v7 (passing). All cross-lane via 16-lane row-confined DPP.

#define NF_OUT 996
#define NSAMP  80000
#define BPB    249           // 996/4 frames per block
#define TH     0.2f
#define EPS    1e-8f
#define INF_I  0x7FFFFFFF

template<int CTRL>
__device__ __forceinline__ float dpp_add16(float x) {
    int t = __builtin_amdgcn_update_dpp(0, __builtin_bit_cast(int, x), CTRL, 0xF, 0xF, false);
    return x + __builtin_bit_cast(float, t);
}
template<int CTRL>
__device__ __forceinline__ int dpp_min16(int x) {
    int t = __builtin_amdgcn_update_dpp(INF_I, x, CTRL, 0xF, 0xF, false);
    return t < x ? t : x;
}
// inclusive sum-scan within each 16-lane row (total lands at l4=15)
__device__ __forceinline__ float scan16_add(float v) {
    v = dpp_add16<0x111>(v);   // row_shr:1
    v = dpp_add16<0x112>(v);   // row_shr:2
    v = dpp_add16<0x114>(v);   // row_shr:4
    v = dpp_add16<0x118>(v);   // row_shr:8
    return v;
}
// min within each 16-lane row (result at l4=15)
__device__ __forceinline__ int red16_min(int v) {
    v = dpp_min16<0x111>(v);
    v = dpp_min16<0x112>(v);
    v = dpp_min16<0x114>(v);
    v = dpp_min16<0x118>(v);
    return v;
}

// correlation MAC: 32 fma for r_k (k=1..8, j=4c+q) + 4 fma for EA (QF).
// W[m] = stream[4c+m] held in W0,W1,W2 ; FR = f[4c..4c+3] (bcast).
#define MACR8(FR, W0, W1, W2) do {                                             \
    r1=fmaf(FR.x,W0.y,r1); r2=fmaf(FR.x,W0.z,r2);                              \
    r3=fmaf(FR.x,W0.w,r3); r4=fmaf(FR.x,W1.x,r4);                              \
    r5=fmaf(FR.x,W1.y,r5); r6=fmaf(FR.x,W1.z,r6);                              \
    r7=fmaf(FR.x,W1.w,r7); r8=fmaf(FR.x,W2.x,r8);                              \
    r1=fmaf(FR.y,W0.z,r1); r2=fmaf(FR.y,W0.w,r2);                              \
    r3=fmaf(FR.y,W1.x,r3); r4=fmaf(FR.y,W1.y,r4);                              \
    r5=fmaf(FR.y,W1.z,r5); r6=fmaf(FR.y,W1.w,r6);                              \
    r7=fmaf(FR.y,W2.x,r7); r8=fmaf(FR.y,W2.y,r8);                              \
    r1=fmaf(FR.z,W0.w,r1); r2=fmaf(FR.z,W1.x,r2);                              \
    r3=fmaf(FR.z,W1.y,r3); r4=fmaf(FR.z,W1.z,r4);                              \
    r5=fmaf(FR.z,W1.w,r5); r6=fmaf(FR.z,W2.x,r6);                              \
    r7=fmaf(FR.z,W2.y,r7); r8=fmaf(FR.z,W2.z,r8);                              \
    r1=fmaf(FR.w,W1.x,r1); r2=fmaf(FR.w,W1.y,r2);                              \
    r3=fmaf(FR.w,W1.z,r3); r4=fmaf(FR.w,W1.w,r4);                              \
    r5=fmaf(FR.w,W2.x,r5); r6=fmaf(FR.w,W2.y,r6);                              \
    r7=fmaf(FR.w,W2.z,r7); r8=fmaf(FR.w,W2.w,r8);                              \
    QF=fmaf(FR.x,FR.x,QF); QF=fmaf(FR.y,FR.y,QF);                              \
    QF=fmaf(FR.z,FR.z,QF); QF=fmaf(FR.w,FR.w,QF);                              \
} while (0)

__global__ __launch_bounds__(64) void yin_kernel(const float* __restrict__ x,
                                                 float* __restrict__ out) {
    const int bx = blockIdx.x;
    const int b  = bx / BPB;
    const int fb = bx - b * BPB;
    const float* __restrict__ xrow = x + (size_t)b * NSAMP + (size_t)fb * 320;

    __shared__ __align__(16) float sch[512];
    const int t = threadIdx.x;          // 0..63
    *(float4*)(sch + 4 * t)       = *(const float4*)(xrow + 4 * t);
    *(float4*)(sch + 4 * t + 256) = *(const float4*)(xrow + 4 * t + 256);
    __syncthreads();

    const int q  = t >> 4;              // quarter = frame select (0..3)
    const int l4 = t & 15;
    const float* f  = sch + 80 * q;     // frame base (16B aligned)
    const float* gp = f + 8 * l4;       // stream base (16B aligned)

    // ---- r(tau), tau = 8*l4+1 .. 8*l4+8, + EA accumulation ----
    float4 R0 = *(const float4*)(gp);
    float4 R1 = *(const float4*)(gp + 4);
    float4 R2 = *(const float4*)(gp + 8);
    float4 R3;
    const float4 S0 = R0, S1 = R1;      // stream m = 0..7
    float r1=0.f,r2=0.f,r3=0.f,r4=0.f,r5=0.f,r6=0.f,r7=0.f,r8=0.f,QF=0.f;

    for (int c = 0; c < 32; c += 4) {   // chunks 0..31 (j = 0..127)
        float4 FR;
        R3 = *(const float4*)(gp + 4*c + 12); FR = *(const float4*)(f + 4*c);      MACR8(FR, R0, R1, R2);
        R0 = *(const float4*)(gp + 4*c + 16); FR = *(const float4*)(f + 4*c + 4);  MACR8(FR, R1, R2, R3);
        R1 = *(const float4*)(gp + 4*c + 20); FR = *(const float4*)(f + 4*c + 8);  MACR8(FR, R2, R3, R0);
        R2 = *(const float4*)(gp + 4*c + 24); FR = *(const float4*)(f + 4*c + 12); MACR8(FR, R3, R0, R1);
    }
    // after loop: R0 = stream[128..131], R1 = stream[132..135], R2 = stream[136..139]
    const float4 R35 = *(const float4*)(gp + 140);      // stream[140..143]
    {   // chunk 32: j = 128..131
        float4 FR = *(const float4*)(f + 128);
        MACR8(FR, R0, R1, R2);
    }
    const float frx = f[132];
    {   // j = 132: r_k += f[132]*stream[132+k]
        r1=fmaf(frx,R1.y,r1); r2=fmaf(frx,R1.z,r2);
        r3=fmaf(frx,R1.w,r3); r4=fmaf(frx,R2.x,r4);
        r5=fmaf(frx,R2.y,r5); r6=fmaf(frx,R2.z,r6);
        r7=fmaf(frx,R2.w,r7); r8=fmaf(frx,R35.x,r8);
        QF = fmaf(frx, frx, QF);
    }
    const float EA = QF;                // sum_{j=0..132} f[j]^2 (uniform/quarter)

    // ---- EB via D-prefix: D_t = x[t+132]^2 - x[t-1]^2, t = 8*l4+k ----
    float hi[8] = {R1.y,R1.z,R1.w,R2.x,R2.y,R2.z,R2.w,R35.x};  // stream[133..140]
    float lo[8] = {S0.x,S0.y,S0.z,S0.w,S1.x,S1.y,S1.z,S1.w};   // stream[0..7]
    float P1,P2,P3,P4,P5,P6,P7,P8;
    {
        float D;
        D = fmaf(hi[0],hi[0], -(lo[0]*lo[0])); P1 = D;
        D = fmaf(hi[1],hi[1], -(lo[1]*lo[1])); P2 = P1 + D;
        D = fmaf(hi[2],hi[2], -(lo[2]*lo[2])); P3 = P2 + D;
        D = fmaf(hi[3],hi[3], -(lo[3]*lo[3])); P4 = P3 + D;
        D = fmaf(hi[4],hi[4], -(lo[4]*lo[4])); P5 = P4 + D;
        D = fmaf(hi[5],hi[5], -(lo[5]*lo[5])); P6 = P5 + D;
        D = fmaf(hi[6],hi[6], -(lo[6]*lo[6])); P7 = P6 + D;
        D = fmaf(hi[7],hi[7], -(lo[7]*lo[7])); P8 = P7 + D;
    }
    float inclD = scan16_add(P8);
    float exclD = inclD - P8;
    const float base = 2.0f * EA + exclD;   // d_k = base + P_k - 2 r_k
    float a1 = fmaf(-2.f, r1, base + P1);
    float a2 = fmaf(-2.f, r2, base + P2);
    float a3 = fmaf(-2.f, r3, base + P3);
    float a4 = fmaf(-2.f, r4, base + P4);
    float a5 = fmaf(-2.f, r5, base + P5);
    float a6 = fmaf(-2.f, r6, base + P6);
    float a7 = fmaf(-2.f, r7, base + P7);
    float a8 = fmaf(-2.f, r8, base + P8);

    // ---- tail taus 129..133 (direct form, register j-split as v7) ----
    float SA[8]  = {S0.x,S0.y,S0.z,S0.w,S1.x,S1.y,S1.z,S1.w};
    float WA[13] = {R0.x,R0.y,R0.z,R0.w,R1.x,R1.y,R1.z,R1.w,
                    R2.x,R2.y,R2.z,R2.w,R35.x};   // WA[m] = stream[128+m]
    float p[5] = {0.f,0.f,0.f,0.f,0.f};
    #pragma unroll
    for (int k = 0; k < 5; ++k) {
        #pragma unroll
        for (int r = 0; r < 8; ++r) {
            float d_ = SA[r] - WA[1 + k + r];     // f[j] - f[j+129+k]
            p[k] = fmaf(d_, d_, p[k]);
        }
    }
    if (l4 < 5) {   // leftover j = 128..132, one per lane
        float fA = f[128 + l4];
        #pragma unroll
        for (int k = 0; k < 5; ++k) {
            float d_ = fA - f[257 + l4 + k];
            p[k] = fmaf(d_, d_, p[k]);
        }
    }
    #pragma unroll
    for (int k = 0; k < 5; ++k) p[k] = scan16_add(p[k]);   // totals at l4=15

    // ---- CMNDF cum prefix: within-lane serial + 16-lane DPP scan ----
    float s1=a1, s2=s1+a2, s3=s2+a3, s4=s3+a4, s5=s4+a5, s6=s5+a6, s7=s6+a7, s8=s7+a8;
    float incl = scan16_add(s8);
    float excl = incl - s8;
    float c1=excl+s1, c2=excl+s2, c3=excl+s3, c4=excl+s4,
          c5=excl+s5, c6=excl+s6, c7=excl+s7, c8=excl+s8;

    // ---- pick: first tau with d*tau < TH*max(cum,eps), tau >= 20 ----
    int best = INF_I;
    const int tb = 8 * l4;
    if (tb+1 >= 20 && a1*(float)(tb+1) < TH*fmaxf(c1,EPS)) best = tb+1;
    if (best==INF_I && tb+2 >= 20 && a2*(float)(tb+2) < TH*fmaxf(c2,EPS)) best = tb+2;
    if (best==INF_I && tb+3 >= 20 && a3*(float)(tb+3) < TH*fmaxf(c3,EPS)) best = tb+3;
    if (best==INF_I && tb+4 >= 20 && a4*(float)(tb+4) < TH*fmaxf(c4,EPS)) best = tb+4;
    if (best==INF_I && tb+5 >= 20 && a5*(float)(tb+5) < TH*fmaxf(c5,EPS)) best = tb+5;
    if (best==INF_I && tb+6 >= 20 && a6*(float)(tb+6) < TH*fmaxf(c6,EPS)) best = tb+6;
    if (best==INF_I && tb+7 >= 20 && a7*(float)(tb+7) < TH*fmaxf(c7,EPS)) best = tb+7;
    if (best==INF_I && tb+8 >= 20 && a8*(float)(tb+8) < TH*fmaxf(c8,EPS)) best = tb+8;
    best = red16_min(best);             // min tau of quarter at l4=15

    if (l4 == 15) {                     // holds cum[128]=c8 and scanned p[k]
        float cum = c8;
        #pragma unroll
        for (int k = 0; k < 5; ++k) {
            cum += p[k];
            if (p[k] * (float)(129 + k) < TH * fmaxf(cum, EPS))
                best = (best < 129 + k) ? best : (129 + k);
        }
        out[(size_t)b * NF_OUT + fb * 4 + q] =
            (best == INF_I) ? 0.0f : 8000.0f / (float)best;
    }
}

extern "C" void kernel_launch(void* const* d_in, const int* in_sizes, int n_in,
                              void* d_out, int out_size, void* d_ws, size_t ws_size,
                              hipStream_t stream) {
    (void)in_sizes; (void)n_in; (void)d_ws; (void)ws_size; (void)out_size;
    const float* x = (const float*)d_in[0];
    float* out = (float*)d_out;
    yin_kernel<<<dim3(8 * BPB), dim3(64), 0, stream>>>(x, out);
}

// Round 9
// 15.078 us; speedup vs baseline: 1.2983x; 1.2983x over previous
//
#include <hip/hip_runtime.h>

// YIN pitch, B=8, n=80000, fp32. SR=8000 HOP=80 TAU_MIN=20 TAU_MAX=133 W=133
// FRAME_LEN=266 THRESH=0.2 ; n_frames=997, output 996/batch.
//
// v9 = revert to v5 (best of session, 15.2 us). Correlation form:
//   d(tau) = EA + EB(tau) - 2*r(tau)
//   r(tau)  = sum_j f[j]*f[j+tau]          (16 fma / 4-j chunk, no subs)
//   EB(tau) = running sum Q of stream squares (4 fma/chunk) + edge terms
//   EA      = sum_{j<133} f[j]^2 (per-lane square + DPP scan + 1 shfl bcast)
// 192 thr = 3 waves = 6 frames/block, half-wave (32 lanes) per frame, lane
// owns tau = 4*l2+1..4*l2+4; tail taus 129..133 j-split; all cross-lane via
// DPP; no divides (d*tau < TH*max(cum,eps)). __launch_bounds__(192,4).
//
// Session post-mortem (R1-R8): five structurally distinct variants spanning
// 2x ranges in VALU/frame and DS/frame all land 15-20 us; effective clock
// during these tiny kernels is ~1 GHz (idle DVFS), and the duration is a
// latency/ramp floor insensitive to instruction counts. v5 was the best
// measured point (4 waves/SIMD TLP + lowest combined pipe load).

#define NF_OUT 996
#define NSAMP  80000
#define FPB    6
#define BPB    (NF_OUT / FPB)   // 166
#define CHUNKD 672              // staged samples per block (16B padded)
#define TH     0.2f
#define EPS    1e-8f

template<int CTRL>
__device__ __forceinline__ float dpp_add_f(float x) {
    int t = __builtin_amdgcn_update_dpp(0, __builtin_bit_cast(int, x), CTRL, 0xF, 0xF, false);
    return x + __builtin_bit_cast(float, t);
}
__device__ __forceinline__ float dpp_b15_add_f(float x) {   // rows 1,3 += lane15/47
    int t = __builtin_amdgcn_update_dpp(0, __builtin_bit_cast(int, x), 0x142, 0xA, 0xF, false);
    return x + __builtin_bit_cast(float, t);
}
template<int CTRL>
__device__ __forceinline__ int dpp_min_i(int x) {
    int t = __builtin_amdgcn_update_dpp(0x7FFFFFFF, x, CTRL, 0xF, 0xF, false);
    return (t < x) ? t : x;
}
__device__ __forceinline__ int dpp_b15_min_i(int x) {
    int t = __builtin_amdgcn_update_dpp(0x7FFFFFFF, x, 0x142, 0xA, 0xF, false);
    return (t < x) ? t : x;
}
// inclusive 32-lane scan (per half-wave); lane31/63 end with the half's total
__device__ __forceinline__ float scan32_add(float v) {
    v = dpp_add_f<0x111>(v);
    v = dpp_add_f<0x112>(v);
    v = dpp_add_f<0x114>(v);
    v = dpp_add_f<0x118>(v);
    v = dpp_b15_add_f(v);
    return v;
}
__device__ __forceinline__ int red32_min(int v) {
    v = dpp_min_i<0x111>(v);
    v = dpp_min_i<0x112>(v);
    v = dpp_min_i<0x114>(v);
    v = dpp_min_i<0x118>(v);
    v = dpp_b15_min_i(v);
    return v;
}

// correlation MAC: r_q += fr[jj] * w_{jj+q}; Q += nxt^2 terms. 20 fma total.
#define MACR(CURV, NXTV, FRV) do {                                             \
    float w0=CURV.y,w1=CURV.z,w2=CURV.w,w3=NXTV.x,w4=NXTV.y,w5=NXTV.z,w6=NXTV.w; \
    r0 = fmaf(FRV.x,w0,r0); r1 = fmaf(FRV.x,w1,r1);                            \
    r2 = fmaf(FRV.x,w2,r2); r3 = fmaf(FRV.x,w3,r3);                            \
    r0 = fmaf(FRV.y,w1,r0); r1 = fmaf(FRV.y,w2,r1);                            \
    r2 = fmaf(FRV.y,w3,r2); r3 = fmaf(FRV.y,w4,r3);                            \
    r0 = fmaf(FRV.z,w2,r0); r1 = fmaf(FRV.z,w3,r1);                            \
    r2 = fmaf(FRV.z,w4,r2); r3 = fmaf(FRV.z,w5,r3);                            \
    r0 = fmaf(FRV.w,w3,r0); r1 = fmaf(FRV.w,w4,r1);                            \
    r2 = fmaf(FRV.w,w5,r2); r3 = fmaf(FRV.w,w6,r3);                            \
    Q  = fmaf(NXTV.x,NXTV.x,Q); Q = fmaf(NXTV.y,NXTV.y,Q);                     \
    Q  = fmaf(NXTV.z,NXTV.z,Q); Q = fmaf(NXTV.w,NXTV.w,Q);                     \
} while (0)

__global__ __launch_bounds__(192, 4) void yin_kernel(const float* __restrict__ x,
                                                     float* __restrict__ out) {
    const int bx = blockIdx.x;
    const int b  = bx / BPB;
    const int fb = bx - b * BPB;
    const float* __restrict__ xrow = x + (size_t)b * NSAMP + (size_t)fb * (FPB * 80);

    __shared__ __align__(16) float sch[CHUNKD];
    const int t = threadIdx.x;
    {
        int t4 = t * 4;
        if (t4 < CHUNKD)
            *(float4*)(sch + t4) = *(const float4*)(xrow + t4);
    }
    __syncthreads();

    const int lane = t & 63;
    const int w    = t >> 6;        // wave id 0..2
    const int h    = lane >> 5;     // half: frame select
    const int l2   = lane & 31;
    const float* f  = sch + (2 * w + h) * 80;   // this half's frame
    const float* gp = f + 4 * l2;               // stream base (16B aligned)

    // ---- r(tau) + Q, tau = 4*l2+1 .. 4*l2+4 ----
    float4 cur = *(const float4*)(gp);          // chunk 0 (m=0..3)
    const float4 S0 = cur;
    float4 nxt;
    float r0 = 0.f, r1 = 0.f, r2 = 0.f, r3 = 0.f, Q = 0.f;

    #pragma unroll 4
    for (int c = 0; c < 32; ++c) {              // j = 4c..4c+3 (j<=127)
        nxt = *(const float4*)(gp + 4 * (c + 1));
        float4 fr = *(const float4*)(f + 4 * c);
        MACR(cur, nxt, fr);
        cur = nxt;
    }
    const float4 C32 = cur;                     // stream m = 128..131
    float4 FR32;
    {   // c = 32 (j = 128..131)
        nxt = *(const float4*)(gp + 4 * 33);
        FR32 = *(const float4*)(f + 128);
        MACR(cur, nxt, FR32);
        cur = nxt;
    }
    const float4 C33 = cur;                     // m = 132..135
    const float4 C34 = *(const float4*)(gp + 4 * 34);   // m = 136..139
    const float frx = f[132];
    {   // j = 132
        r0 = fmaf(frx, C33.y, r0);
        r1 = fmaf(frx, C33.z, r1);
        r2 = fmaf(frx, C33.w, r2);
        r3 = fmaf(frx, C34.x, r3);
    }

    // ---- EB(tau): Q covers stream m'=4..135; adjust edges ----
    const float sy = S0.y * S0.y, sz = S0.z * S0.z, sw = S0.w * S0.w;
    const float zC = C33.z * C33.z, wC = C33.w * C33.w, x34 = C34.x * C34.x;
    const float EB0 = Q + sy + sz + sw - zC - wC;   // m' 1..133
    const float EB1 = Q + sz + sw - wC;             // m' 2..134
    const float EB2 = Q + sw;                       // m' 3..135
    const float EB3 = Q + x34;                      // m' 4..136

    // ---- EA = sum_{j<133} f[j]^2 (per half uniform) ----
    float sq4 = fmaf(S0.x, S0.x, fmaf(S0.y, S0.y, fmaf(S0.z, S0.z, S0.w * S0.w)));
    float tot128 = __shfl(scan32_add(sq4), 31, 32);   // sum_{j<128}, all lanes
    float EA = tot128 + FR32.x * FR32.x + FR32.y * FR32.y
             + FR32.z * FR32.z + FR32.w * FR32.w + frx * frx;

    // ---- d(tau) ----
    const float a0 = fmaf(-2.f, r0, EA + EB0);
    const float a1 = fmaf(-2.f, r1, EA + EB1);
    const float a2 = fmaf(-2.f, r2, EA + EB2);
    const float a3 = fmaf(-2.f, r3, EA + EB3);

    // ---- tail taus 129..133 (direct form, j-split) ----
    float sm[8] = {C32.y, C32.z, C32.w, C33.x, C33.y, C33.z, C33.w, C34.x};
    float s0a[4] = {S0.x, S0.y, S0.z, S0.w};
    float p[5] = {0.f, 0.f, 0.f, 0.f, 0.f};
    #pragma unroll
    for (int k = 0; k < 5; ++k) {
        #pragma unroll
        for (int q = 0; q < 4; ++q) {
            float d_ = s0a[q] - sm[k + q];
            p[k] = fmaf(d_, d_, p[k]);
        }
    }
    if (l2 < 5) {   // leftover j = 128..132, one per lane
        float av = f[128 + l2];
        #pragma unroll
        for (int k = 0; k < 5; ++k) {
            float d_ = av - f[257 + l2 + k];
            p[k] = fmaf(d_, d_, p[k]);
        }
    }
    #pragma unroll
    for (int k = 0; k < 5; ++k) p[k] = scan32_add(p[k]);   // total at lane31/63

    // ---- CMNDF cum prefix (registers + DPP) ----
    float L = a0 + a1 + a2 + a3;
    float inc = scan32_add(L);
    float excl = inc - L;
    float c0 = excl + a0;
    float c1 = c0 + a1;
    float c2 = c1 + a2;
    float c3 = c2 + a3;

    // ---- candidate pick: d*tau < TH*max(cum,eps), tau >= 20 ----
    int best = 0x7FFFFFFF;
    const int tau0 = 4 * l2 + 1;
    if (tau0     >= 20 && a0 * (float)(tau0)     < TH * fmaxf(c0, EPS)) best = tau0;
    if (best == 0x7FFFFFFF && tau0 + 1 >= 20 && a1 * (float)(tau0 + 1) < TH * fmaxf(c1, EPS)) best = tau0 + 1;
    if (best == 0x7FFFFFFF && tau0 + 2 >= 20 && a2 * (float)(tau0 + 2) < TH * fmaxf(c2, EPS)) best = tau0 + 2;
    if (best == 0x7FFFFFFF && tau0 + 3 >= 20 && a3 * (float)(tau0 + 3) < TH * fmaxf(c3, EPS)) best = tau0 + 3;

    if (l2 == 31) {     // this lane holds cum[128] and the reduced p[k]
        float cum = c3;
        #pragma unroll
        for (int k = 0; k < 5; ++k) {
            cum += p[k];
            if (p[k] * (float)(129 + k) < TH * fmaxf(cum, EPS))
                best = (best < 129 + k) ? best : (129 + k);
        }
    }
    best = red32_min(best);     // half-wave min -> l2=31 (lane 31 and lane 63)

    if (l2 == 31) {
        int fr_idx = fb * FPB + 2 * w + h;
        out[(size_t)b * NF_OUT + fr_idx] =
            (best == 0x7FFFFFFF) ? 0.0f : 8000.0f / (float)best;
    }
}

extern "C" void kernel_launch(void* const* d_in, const int* in_sizes, int n_in,
                              void* d_out, int out_size, void* d_ws, size_t ws_size,
                              hipStream_t stream) {
    (void)in_sizes; (void)n_in; (void)d_ws; (void)ws_size; (void)out_size;
    const float* x = (const float*)d_in[0];
    float* out = (float*)d_out;
    yin_kernel<<<dim3(8 * BPB), dim3(192), 0, stream>>>(x, out);
}